// Round 16
// baseline (50.442 us; speedup 1.0000x reference)
//
#include <hip/hip_runtime.h>

typedef __attribute__((ext_vector_type(8))) short s8v;   // 8 x bf16 (bit pattern)
typedef __attribute__((ext_vector_type(4))) float f4v;

__device__ __forceinline__ float sgm(float x) { return 1.f / (1.f + __expf(-x)); }
__device__ __forceinline__ float tanhq(float x) { return 2.f / (1.f + __expf(-2.f*x)) - 1.f; }
// split f32 -> bf16 hi + bf16 lo (x ~= hi + lo, residual ~2^-17 |x|)
__device__ __forceinline__ void bsplit(float x, short& hi, short& lo) {
    unsigned u = __float_as_uint(x);
    unsigned hb = u & 0xffff0000u;
    hi = (short)(hb >> 16);
    float r = x - __uint_as_float(hb);
    lo = (short)(__float_as_uint(r) >> 16);
}
// quad_perm DPP adds (VALU, not DS): xor1 = 0xB1 ; xor2 = 0x4E
__device__ __forceinline__ float dppadd1(float x) {
    return x + __uint_as_float(__builtin_amdgcn_mov_dpp(__float_as_uint(x), 0xB1, 0xF, 0xF, true));
}
__device__ __forceinline__ float dppadd2(float x) {
    return x + __uint_as_float(__builtin_amdgcn_mov_dpp(__float_as_uint(x), 0x4E, 0xF, 0xF, true));
}

#define SQ 4     // seqs per block; 600 blocks x 4 = 2400 (300 % 4 == 0 -> same b per block)

// Two 16x16 z-tiles per wave (M=32): D_A = gates of cell wl*8+g, D_B = cell wl*8+4+g.
// B/D layout + row-permutation HW-verified rounds 6-15 (absmax 0.0039 vs np ref).
__device__ __forceinline__ void zA2(const short* vh, const short* vl,
    const s8v (&ah)[2][2], const s8v (&al)[2][2], const f4v (&bias)[2],
    int boff, int g, f4v& dA, f4v& dB)
{
    s8v bh0 = *(const s8v*)((const char*)vh + boff +      g*16);
    s8v bh1 = *(const s8v*)((const char*)vh + boff + 64 + g*16);
    s8v bl0 = *(const s8v*)((const char*)vl + boff +      g*16);
    s8v bl1 = *(const s8v*)((const char*)vl + boff + 64 + g*16);
    dA = bias[0];
    dA = __builtin_amdgcn_mfma_f32_16x16x32_bf16(ah[0][0], bh0, dA, 0, 0, 0);
    dA = __builtin_amdgcn_mfma_f32_16x16x32_bf16(ah[0][1], bh1, dA, 0, 0, 0);
    dA = __builtin_amdgcn_mfma_f32_16x16x32_bf16(al[0][0], bh0, dA, 0, 0, 0);
    dA = __builtin_amdgcn_mfma_f32_16x16x32_bf16(al[0][1], bh1, dA, 0, 0, 0);
    dA = __builtin_amdgcn_mfma_f32_16x16x32_bf16(ah[0][0], bl0, dA, 0, 0, 0);
    dA = __builtin_amdgcn_mfma_f32_16x16x32_bf16(ah[0][1], bl1, dA, 0, 0, 0);
    dB = bias[1];
    dB = __builtin_amdgcn_mfma_f32_16x16x32_bf16(ah[1][0], bh0, dB, 0, 0, 0);
    dB = __builtin_amdgcn_mfma_f32_16x16x32_bf16(ah[1][1], bh1, dB, 0, 0, 0);
    dB = __builtin_amdgcn_mfma_f32_16x16x32_bf16(al[1][0], bh0, dB, 0, 0, 0);
    dB = __builtin_amdgcn_mfma_f32_16x16x32_bf16(al[1][1], bh1, dB, 0, 0, 0);
    dB = __builtin_amdgcn_mfma_f32_16x16x32_bf16(ah[1][0], bl0, dB, 0, 0, 0);
    dB = __builtin_amdgcn_mfma_f32_16x16x32_bf16(ah[1][1], bl1, dB, 0, 0, 0);
}

// ===== fused kernel: nbr + GAT attn + LSTM x2 (layer-split MFMA, dbuf, 1 barrier/phase) + FC =====
__global__ __launch_bounds__(512, 4) void k_stgat(
    const float* __restrict__ A,    const float* __restrict__ X,
    const float* __restrict__ Wg,   const float* __restrict__ aat,
    const float* __restrict__ Wih0, const float* __restrict__ Whh0,
    const float* __restrict__ bih0, const float* __restrict__ bhh0,
    const float* __restrict__ Wih1, const float* __restrict__ Whh1,
    const float* __restrict__ bih1, const float* __restrict__ bhh1,
    const float* __restrict__ fcW,  const float* __restrict__ fcb,
    float* __restrict__ out)
{
    __shared__ int   snbr[SQ][64];
    __shared__ int   scnt[SQ];
    __shared__ float shg[SQ*384];                        // local hgat (6 KB)
    __shared__ __align__(16) char uarea[43200];          // B: X[b] slice ; C: v dbuf + sh1f

    const int tid  = threadIdx.x;
    const int w    = tid >> 6;        // wave 0..7
    const int l    = tid & 63;
    const int seq0 = blockIdx.x * SQ;
    const int b    = seq0 / 300, i0 = seq0 - b*300;

    float* Xs = (float*)uarea;

    // ---------- phase A: cooperative X[b] slice load + neighbor lists ----------
    {
        const float* Xg = X + (size_t)b * 10800;
        for (int x = tid; x < 10800; x += 512) Xs[x] = Xg[x];
    }
    if (w < SQ) {                     // wave w builds neighbor list of row i0+w
        int i = i0 + w;
        int c = 0;
        for (int j0 = 0; j0 < 300; j0 += 64) {
            int j = j0 + l;
            bool p = (j < 300) && (A[i*300 + j] != 0.f);
            unsigned long long m = __ballot(p);
            if (p) {
                int pos = __popcll(m & ((1ull << l) - 1ull));
                if (c + pos < 64) snbr[w][c + pos] = j;
            }
            c += __popcll(m);
        }
        if (c > 64) c = 64;
        if (l == 0) scnt[w] = c;
    }
    __syncthreads();

    // ---------- phase B: GAT attention (all 8 waves, max-free softmax, DPP merges) ----------
    {
        const int hh = l >> 3, j8 = l & 7, dd = j8 & 3;
        float wal0=0.f, wal1=0.f, wal2=0.f, war0=0.f, war1=0.f, war2=0.f;
        #pragma unroll
        for (int d4 = 0; d4 < 4; d4++) {
            float av = aat[d4], bv = aat[4+d4];
            const float* wr = Wg + (hh*4+d4)*3;
            wal0 += wr[0]*av; wal1 += wr[1]*av; wal2 += wr[2]*av;
            war0 += wr[0]*bv; war1 += wr[1]*bv; war2 += wr[2]*bv;
        }
        const float* wp = Wg + (hh*4+dd)*3;
        float wp0 = wp[0], wp1 = wp[1], wp2 = wp[2];

        for (int u = 7 - w; u < SQ*12; u += 8) {
            int us = u / 12, t = u - us*12;
            int i = i0 + us;
            int c = scnt[us];

            const float* Xi = Xs + i*36 + t*3;
            float gl = Xi[0]*wal0 + Xi[1]*wal1 + Xi[2]*wal2;

            float s = 0.f, a0 = 0.f, a1 = 0.f, a2 = 0.f;
            for (int kk = j8; kk < c; kk += 8) {
                int j = snbr[us][kk];
                const float* Xj = Xs + j*36 + t*3;
                float y0 = Xj[0], y1 = Xj[1], y2 = Xj[2];
                float e = gl + y0*war0 + y1*war1 + y2*war2;
                e = e > 0.f ? e : 0.2f*e;      // leaky_relu 0.2
                float wt = __expf(e);
                s += wt; a0 += wt*y0; a1 += wt*y1; a2 += wt*y2;
            }
            s  = dppadd1(s);  a0 = dppadd1(a0); a1 = dppadd1(a1); a2 = dppadd1(a2);
            s  = dppadd2(s);  a0 = dppadd2(a0); a1 = dppadd2(a1); a2 = dppadd2(a2);
            s  += __shfl_xor(s, 4, 64);
            a0 += __shfl_xor(a0, 4, 64);
            a1 += __shfl_xor(a1, 4, 64);
            a2 += __shfl_xor(a2, 4, 64);
            if (j8 < 4)
                shg[us*384 + t*32 + hh*4 + dd] = (a0*wp0 + a1*wp1 + a2*wp2) / s;
        }
    }

    // ---------- A-fragments: waves 0-3 = layer 0, waves 4-7 = layer 1 ----------
    const int n16   = l & 15;         // B/D col = seq slot ; A frag row
    const int g     = l >> 4;         // k-group ; D row-quad
    const int wl    = w & 3;
    const int layer = w >> 2;
    const int cA    = wl*8 + g;       // cells owned by this lane
    const int cB    = wl*8 + 4 + g;
    s8v ah[2][2], al[2][2];
    f4v bias[2];
    {
        const float* Wih = layer ? Wih1 : Wih0;
        const float* Whh = layer ? Whh1 : Whh0;
        const float* bi  = layer ? bih1 : bih0;
        const float* bh  = layer ? bhh1 : bhh0;
        #pragma unroll
        for (int tau = 0; tau < 2; tau++) {
            const int arow = (n16 & 3)*32 + wl*8 + tau*4 + (n16 >> 2);   // permuted W row
            const float* si = Wih + arow*32 + g*8;
            const float* sh = Whh + arow*32 + g*8;
            #pragma unroll
            for (int j = 0; j < 8; j++) {
                short h2, l2;
                bsplit(si[j], h2, l2); ah[tau][0][j]=h2; al[tau][0][j]=l2;
                bsplit(sh[j], h2, l2); ah[tau][1][j]=h2; al[tau][1][j]=l2;
            }
            const int cell = wl*8 + tau*4 + g;
            #pragma unroll
            for (int r = 0; r < 4; r++)
                bias[tau][r] = bi[r*32+cell] + bh[r*32+cell];
        }
    }
    __syncthreads();                  // Xs dead; uarea becomes double-buffered v state

    // ---------- phase C layout: vb[buf][lay][hl][16*72] shorts ----------
    short* vb = (short*)uarea;                            // 8 x 1152 shorts = 18432 B
    float* sh1f = (float*)(vb + 8*1152);                  // final h1 for FC
    #define VOFF(buf, lay, hl) ((((buf)*2 + (lay))*2 + (hl))*1152)

    { unsigned* vz = (unsigned*)uarea; for (int x = tid; x < 4608; x += 512) vz[x] = 0; }
    __syncthreads();
    if (tid < SQ*32) {                                    // x(0) -> v0[buf0]
        int us = tid >> 5, uc = tid & 31;
        short h2, l2; bsplit(shg[us*384 + uc], h2, l2);
        vb[VOFF(0,0,0) + us*72 + uc] = h2;  vb[VOFF(0,0,1) + us*72 + uc] = l2;
    }
    __syncthreads();

    const int boff = n16 * 144;
    float csA = 0.f, csB = 0.f;
    int cur = 0;

    auto cellup = [&](f4v z, float& cs) -> float {
        cs = sgm(z[1])*cs + sgm(z[0])*tanhq(z[2]);
        return sgm(z[3])*tanhq(cs);
    };

    // ---- prologue (phase -1): layer-0 computes z0(0); h0(0) -> buf1; x(1) -> buf1 ----
    {
        if (layer == 0) {
            f4v zAa, zBb;
            zA2(vb + VOFF(0,0,0), vb + VOFF(0,0,1), ah, al, bias, boff, g, zAa, zBb);
            float hA = cellup(zAa, csA);
            float hB = cellup(zBb, csB);
            short h2, l2;
            bsplit(hA, h2, l2);
            vb[VOFF(1,0,0) + n16*72 + 32 + cA] = h2;  vb[VOFF(1,0,1) + n16*72 + 32 + cA] = l2;
            vb[VOFF(1,1,0) + n16*72 + cA]      = h2;  vb[VOFF(1,1,1) + n16*72 + cA]      = l2;
            bsplit(hB, h2, l2);
            vb[VOFF(1,0,0) + n16*72 + 32 + cB] = h2;  vb[VOFF(1,0,1) + n16*72 + 32 + cB] = l2;
            vb[VOFF(1,1,0) + n16*72 + cB]      = h2;  vb[VOFF(1,1,1) + n16*72 + cB]      = l2;
        }
        if (tid < SQ*32) {                                // x(1)
            int us = tid >> 5, uc = tid & 31;
            short h2, l2; bsplit(shg[us*384 + 32 + uc], h2, l2);
            vb[VOFF(1,0,0) + us*72 + uc] = h2;  vb[VOFF(1,0,1) + us*72 + uc] = l2;
        }
        __syncthreads();
        cur = 1;
    }

    // ---- main loop: phase p = { z0(p+1) on waves 0-3  ||  z1(p) on waves 4-7 } ----
    for (int p = 0; p < 12; p++) {
        const int nxt = cur ^ 1;
        const bool active = (layer == 1) || (p < 11);
        if (active) {
            f4v zAa, zBb;
            zA2(vb + VOFF(cur,layer,0), vb + VOFF(cur,layer,1), ah, al, bias, boff, g, zAa, zBb);
            float hA = cellup(zAa, csA);
            float hB = cellup(zBb, csB);
            short h2, l2;
            if (layer == 0) {                             // h0(p+1) -> v0next.h0, v1next.h0
                bsplit(hA, h2, l2);
                vb[VOFF(nxt,0,0) + n16*72 + 32 + cA] = h2;  vb[VOFF(nxt,0,1) + n16*72 + 32 + cA] = l2;
                vb[VOFF(nxt,1,0) + n16*72 + cA]      = h2;  vb[VOFF(nxt,1,1) + n16*72 + cA]      = l2;
                bsplit(hB, h2, l2);
                vb[VOFF(nxt,0,0) + n16*72 + 32 + cB] = h2;  vb[VOFF(nxt,0,1) + n16*72 + 32 + cB] = l2;
                vb[VOFF(nxt,1,0) + n16*72 + cB]      = h2;  vb[VOFF(nxt,1,1) + n16*72 + cB]      = l2;
            } else {                                      // h1(p) -> v1next.h1
                bsplit(hA, h2, l2);
                vb[VOFF(nxt,1,0) + n16*72 + 32 + cA] = h2;  vb[VOFF(nxt,1,1) + n16*72 + 32 + cA] = l2;
                bsplit(hB, h2, l2);
                vb[VOFF(nxt,1,0) + n16*72 + 32 + cB] = h2;  vb[VOFF(nxt,1,1) + n16*72 + 32 + cB] = l2;
                if (p == 11 && n16 < SQ) { sh1f[n16*32 + cA] = hA; sh1f[n16*32 + cB] = hB; }
            }
        }
        if (tid < SQ*32 && p + 2 < 12) {                  // stage x(p+2) -> v0next.x
            int us = tid >> 5, uc = tid & 31;
            short h2, l2; bsplit(shg[us*384 + (p+2)*32 + uc], h2, l2);
            vb[VOFF(nxt,0,0) + us*72 + uc] = h2;  vb[VOFF(nxt,0,1) + us*72 + uc] = l2;
        }
        __syncthreads();
        cur = nxt;
    }

    // ---- FC: SQ*36 outputs ----
    if (tid < SQ*36) {
        int s = tid / 36, r = tid - s*36;
        float acc = fcb[r];
        #pragma unroll
        for (int c4 = 0; c4 < 8; c4++) {
            float4 uv = *(const float4*)&fcW[r*32 + 4*c4];
            acc += uv.x*sh1f[s*32+4*c4+0] + uv.y*sh1f[s*32+4*c4+1]
                 + uv.z*sh1f[s*32+4*c4+2] + uv.w*sh1f[s*32+4*c4+3];
        }
        out[(seq0 + s)*36 + r] = acc;
    }
}

extern "C" void kernel_launch(void* const* d_in, const int* in_sizes, int n_in,
                              void* d_out, int out_size, void* d_ws, size_t ws_size,
                              hipStream_t stream)
{
    const float* A    = (const float*)d_in[0];
    const float* X    = (const float*)d_in[1];
    const float* Wg   = (const float*)d_in[2];
    const float* aat  = (const float*)d_in[3];
    const float* Wih0 = (const float*)d_in[4];
    const float* Whh0 = (const float*)d_in[5];
    const float* bih0 = (const float*)d_in[6];
    const float* bhh0 = (const float*)d_in[7];
    const float* Wih1 = (const float*)d_in[8];
    const float* Whh1 = (const float*)d_in[9];
    const float* bih1 = (const float*)d_in[10];
    const float* bhh1 = (const float*)d_in[11];
    const float* fcW  = (const float*)d_in[12];
    const float* fcb  = (const float*)d_in[13];
    float* out = (float*)d_out;

    k_stgat<<<600, 512, 0, stream>>>(A, X, Wg, aat,
                                     Wih0, Whh0, bih0, bhh0,
                                     Wih1, Whh1, bih1, bhh1,
                                     fcW, fcb, out);
}

// Round 17
// 36.334 us; speedup vs baseline: 1.3883x; 1.3883x over previous
//
#include <hip/hip_runtime.h>

typedef __attribute__((ext_vector_type(8))) short s8v;   // 8 x bf16 (bit pattern)
typedef __attribute__((ext_vector_type(4))) float f4v;

__device__ __forceinline__ float sgm(float x) { return 1.f / (1.f + __expf(-x)); }
__device__ __forceinline__ float tanhq(float x) { return 2.f / (1.f + __expf(-2.f*x)) - 1.f; }
// split f32 -> bf16 hi + bf16 lo (x ~= hi + lo, residual ~2^-17 |x|)
__device__ __forceinline__ void bsplit(float x, short& hi, short& lo) {
    unsigned u = __float_as_uint(x);
    unsigned hb = u & 0xffff0000u;
    hi = (short)(hb >> 16);
    float r = x - __uint_as_float(hb);
    lo = (short)(__float_as_uint(r) >> 16);
}
// quad_perm DPP adds (VALU, not DS): xor1 = 0xB1 ; xor2 = 0x4E
__device__ __forceinline__ float dppadd1(float x) {
    return x + __uint_as_float(__builtin_amdgcn_mov_dpp(__float_as_uint(x), 0xB1, 0xF, 0xF, true));
}
__device__ __forceinline__ float dppadd2(float x) {
    return x + __uint_as_float(__builtin_amdgcn_mov_dpp(__float_as_uint(x), 0x4E, 0xF, 0xF, true));
}

#define SQ 5     // seqs per block; 480 blocks x 5 = 2400 (same b per block)
                 // SQ=4/600blk regressed (r16: per-block overhead invariant in SQ);
                 // SQ=8..16/fewer blocks regressed (r12-14: serial span exposed).

// Two 16x16 z-tiles per wave (M=32): D_A = gates of cell wl*8+g, D_B = cell wl*8+4+g.
// B/D layout + row-permutation HW-verified rounds 6-16 (absmax 0.0039 vs np ref).
__device__ __forceinline__ void zA2(const short* vh, const short* vl,
    const s8v (&ah)[2][2], const s8v (&al)[2][2], const f4v (&bias)[2],
    int boff, int g, f4v& dA, f4v& dB)
{
    s8v bh0 = *(const s8v*)((const char*)vh + boff +      g*16);
    s8v bh1 = *(const s8v*)((const char*)vh + boff + 64 + g*16);
    s8v bl0 = *(const s8v*)((const char*)vl + boff +      g*16);
    s8v bl1 = *(const s8v*)((const char*)vl + boff + 64 + g*16);
    dA = bias[0];
    dA = __builtin_amdgcn_mfma_f32_16x16x32_bf16(ah[0][0], bh0, dA, 0, 0, 0);
    dA = __builtin_amdgcn_mfma_f32_16x16x32_bf16(ah[0][1], bh1, dA, 0, 0, 0);
    dA = __builtin_amdgcn_mfma_f32_16x16x32_bf16(al[0][0], bh0, dA, 0, 0, 0);
    dA = __builtin_amdgcn_mfma_f32_16x16x32_bf16(al[0][1], bh1, dA, 0, 0, 0);
    dA = __builtin_amdgcn_mfma_f32_16x16x32_bf16(ah[0][0], bl0, dA, 0, 0, 0);
    dA = __builtin_amdgcn_mfma_f32_16x16x32_bf16(ah[0][1], bl1, dA, 0, 0, 0);
    dB = bias[1];
    dB = __builtin_amdgcn_mfma_f32_16x16x32_bf16(ah[1][0], bh0, dB, 0, 0, 0);
    dB = __builtin_amdgcn_mfma_f32_16x16x32_bf16(ah[1][1], bh1, dB, 0, 0, 0);
    dB = __builtin_amdgcn_mfma_f32_16x16x32_bf16(al[1][0], bh0, dB, 0, 0, 0);
    dB = __builtin_amdgcn_mfma_f32_16x16x32_bf16(al[1][1], bh1, dB, 0, 0, 0);
    dB = __builtin_amdgcn_mfma_f32_16x16x32_bf16(ah[1][0], bl0, dB, 0, 0, 0);
    dB = __builtin_amdgcn_mfma_f32_16x16x32_bf16(ah[1][1], bl1, dB, 0, 0, 0);
}

// ===== fused kernel: nbr + GAT attn + LSTM x2 (layer-split MFMA, dbuf, 1 barrier/phase) + FC =====
__global__ __launch_bounds__(512, 4) void k_stgat(
    const float* __restrict__ A,    const float* __restrict__ X,
    const float* __restrict__ Wg,   const float* __restrict__ aat,
    const float* __restrict__ Wih0, const float* __restrict__ Whh0,
    const float* __restrict__ bih0, const float* __restrict__ bhh0,
    const float* __restrict__ Wih1, const float* __restrict__ Whh1,
    const float* __restrict__ bih1, const float* __restrict__ bhh1,
    const float* __restrict__ fcW,  const float* __restrict__ fcb,
    float* __restrict__ out)
{
    __shared__ int   snbr[SQ][64];
    __shared__ int   scnt[SQ];
    __shared__ float shg[SQ*384];                        // local hgat (7.5 KB)
    __shared__ __align__(16) char uarea[43200];          // B: X[b] slice ; C: v dbuf + sh1f

    const int tid  = threadIdx.x;
    const int w    = tid >> 6;        // wave 0..7
    const int l    = tid & 63;
    const int seq0 = blockIdx.x * SQ;
    const int b    = seq0 / 300, i0 = seq0 - b*300;

    float* Xs = (float*)uarea;

    // ---------- phase A: cooperative X[b] slice load + neighbor lists ----------
    {
        const float* Xg = X + (size_t)b * 10800;
        for (int x = tid; x < 10800; x += 512) Xs[x] = Xg[x];
    }
    if (w < SQ) {                     // wave w builds neighbor list of row i0+w
        int i = i0 + w;
        int c = 0;
        for (int j0 = 0; j0 < 300; j0 += 64) {
            int j = j0 + l;
            bool p = (j < 300) && (A[i*300 + j] != 0.f);
            unsigned long long m = __ballot(p);
            if (p) {
                int pos = __popcll(m & ((1ull << l) - 1ull));
                if (c + pos < 64) snbr[w][c + pos] = j;
            }
            c += __popcll(m);
        }
        if (c > 64) c = 64;
        if (l == 0) scnt[w] = c;
    }
    __syncthreads();

    // ---------- phase B: GAT attention (all 8 waves, max-free softmax, DPP merges) ----------
    {
        const int hh = l >> 3, j8 = l & 7, dd = j8 & 3;
        float wal0=0.f, wal1=0.f, wal2=0.f, war0=0.f, war1=0.f, war2=0.f;
        #pragma unroll
        for (int d4 = 0; d4 < 4; d4++) {
            float av = aat[d4], bv = aat[4+d4];
            const float* wr = Wg + (hh*4+d4)*3;
            wal0 += wr[0]*av; wal1 += wr[1]*av; wal2 += wr[2]*av;
            war0 += wr[0]*bv; war1 += wr[1]*bv; war2 += wr[2]*bv;
        }
        const float* wp = Wg + (hh*4+dd)*3;
        float wp0 = wp[0], wp1 = wp[1], wp2 = wp[2];

        for (int u = 7 - w; u < SQ*12; u += 8) {
            int us = u / 12, t = u - us*12;
            int i = i0 + us;
            int c = scnt[us];

            const float* Xi = Xs + i*36 + t*3;
            float gl = Xi[0]*wal0 + Xi[1]*wal1 + Xi[2]*wal2;

            float s = 0.f, a0 = 0.f, a1 = 0.f, a2 = 0.f;
            for (int kk = j8; kk < c; kk += 8) {
                int j = snbr[us][kk];
                const float* Xj = Xs + j*36 + t*3;
                float y0 = Xj[0], y1 = Xj[1], y2 = Xj[2];
                float e = gl + y0*war0 + y1*war1 + y2*war2;
                e = e > 0.f ? e : 0.2f*e;      // leaky_relu 0.2
                float wt = __expf(e);
                s += wt; a0 += wt*y0; a1 += wt*y1; a2 += wt*y2;
            }
            s  = dppadd1(s);  a0 = dppadd1(a0); a1 = dppadd1(a1); a2 = dppadd1(a2);
            s  = dppadd2(s);  a0 = dppadd2(a0); a1 = dppadd2(a1); a2 = dppadd2(a2);
            s  += __shfl_xor(s, 4, 64);
            a0 += __shfl_xor(a0, 4, 64);
            a1 += __shfl_xor(a1, 4, 64);
            a2 += __shfl_xor(a2, 4, 64);
            if (j8 < 4)
                shg[us*384 + t*32 + hh*4 + dd] = (a0*wp0 + a1*wp1 + a2*wp2) / s;
        }
    }

    // ---------- A-fragments: waves 0-3 = layer 0, waves 4-7 = layer 1 ----------
    const int n16   = l & 15;         // B/D col = seq slot ; A frag row
    const int g     = l >> 4;         // k-group ; D row-quad
    const int wl    = w & 3;
    const int layer = w >> 2;
    const int cA    = wl*8 + g;       // cells owned by this lane
    const int cB    = wl*8 + 4 + g;
    s8v ah[2][2], al[2][2];
    f4v bias[2];
    {
        const float* Wih = layer ? Wih1 : Wih0;
        const float* Whh = layer ? Whh1 : Whh0;
        const float* bi  = layer ? bih1 : bih0;
        const float* bh  = layer ? bhh1 : bhh0;
        #pragma unroll
        for (int tau = 0; tau < 2; tau++) {
            const int arow = (n16 & 3)*32 + wl*8 + tau*4 + (n16 >> 2);   // permuted W row
            const float* si = Wih + arow*32 + g*8;
            const float* sh = Whh + arow*32 + g*8;
            #pragma unroll
            for (int j = 0; j < 8; j++) {
                short h2, l2;
                bsplit(si[j], h2, l2); ah[tau][0][j]=h2; al[tau][0][j]=l2;
                bsplit(sh[j], h2, l2); ah[tau][1][j]=h2; al[tau][1][j]=l2;
            }
            const int cell = wl*8 + tau*4 + g;
            #pragma unroll
            for (int r = 0; r < 4; r++)
                bias[tau][r] = bi[r*32+cell] + bh[r*32+cell];
        }
    }
    __syncthreads();                  // Xs dead; uarea becomes double-buffered v state

    // ---------- phase C layout: vb[buf][lay][hl][16*72] shorts ----------
    short* vb = (short*)uarea;                            // 8 x 1152 shorts = 18432 B
    float* sh1f = (float*)(vb + 8*1152);                  // final h1 for FC (640 B)
    #define VOFF(buf, lay, hl) ((((buf)*2 + (lay))*2 + (hl))*1152)

    { unsigned* vz = (unsigned*)uarea; for (int x = tid; x < 4608; x += 512) vz[x] = 0; }
    __syncthreads();
    if (tid < SQ*32) {                                    // x(0) -> v0[buf0]
        int us = tid >> 5, uc = tid & 31;
        short h2, l2; bsplit(shg[us*384 + uc], h2, l2);
        vb[VOFF(0,0,0) + us*72 + uc] = h2;  vb[VOFF(0,0,1) + us*72 + uc] = l2;
    }
    __syncthreads();

    const int boff = n16 * 144;
    float csA = 0.f, csB = 0.f;
    int cur = 0;

    auto cellup = [&](f4v z, float& cs) -> float {
        cs = sgm(z[1])*cs + sgm(z[0])*tanhq(z[2]);
        return sgm(z[3])*tanhq(cs);
    };

    // ---- prologue (phase -1): layer-0 computes z0(0); h0(0) -> buf1; x(1) -> buf1 ----
    {
        if (layer == 0) {
            f4v zAa, zBb;
            zA2(vb + VOFF(0,0,0), vb + VOFF(0,0,1), ah, al, bias, boff, g, zAa, zBb);
            float hA = cellup(zAa, csA);
            float hB = cellup(zBb, csB);
            short h2, l2;
            bsplit(hA, h2, l2);
            vb[VOFF(1,0,0) + n16*72 + 32 + cA] = h2;  vb[VOFF(1,0,1) + n16*72 + 32 + cA] = l2;
            vb[VOFF(1,1,0) + n16*72 + cA]      = h2;  vb[VOFF(1,1,1) + n16*72 + cA]      = l2;
            bsplit(hB, h2, l2);
            vb[VOFF(1,0,0) + n16*72 + 32 + cB] = h2;  vb[VOFF(1,0,1) + n16*72 + 32 + cB] = l2;
            vb[VOFF(1,1,0) + n16*72 + cB]      = h2;  vb[VOFF(1,1,1) + n16*72 + cB]      = l2;
        }
        if (tid < SQ*32) {                                // x(1)
            int us = tid >> 5, uc = tid & 31;
            short h2, l2; bsplit(shg[us*384 + 32 + uc], h2, l2);
            vb[VOFF(1,0,0) + us*72 + uc] = h2;  vb[VOFF(1,0,1) + us*72 + uc] = l2;
        }
        __syncthreads();
        cur = 1;
    }

    // ---- main loop: phase p = { z0(p+1) on waves 0-3  ||  z1(p) on waves 4-7 } ----
    for (int p = 0; p < 12; p++) {
        const int nxt = cur ^ 1;
        const bool active = (layer == 1) || (p < 11);
        if (active) {
            f4v zAa, zBb;
            zA2(vb + VOFF(cur,layer,0), vb + VOFF(cur,layer,1), ah, al, bias, boff, g, zAa, zBb);
            float hA = cellup(zAa, csA);
            float hB = cellup(zBb, csB);
            short h2, l2;
            if (layer == 0) {                             // h0(p+1) -> v0next.h0, v1next.h0
                bsplit(hA, h2, l2);
                vb[VOFF(nxt,0,0) + n16*72 + 32 + cA] = h2;  vb[VOFF(nxt,0,1) + n16*72 + 32 + cA] = l2;
                vb[VOFF(nxt,1,0) + n16*72 + cA]      = h2;  vb[VOFF(nxt,1,1) + n16*72 + cA]      = l2;
                bsplit(hB, h2, l2);
                vb[VOFF(nxt,0,0) + n16*72 + 32 + cB] = h2;  vb[VOFF(nxt,0,1) + n16*72 + 32 + cB] = l2;
                vb[VOFF(nxt,1,0) + n16*72 + cB]      = h2;  vb[VOFF(nxt,1,1) + n16*72 + cB]      = l2;
            } else {                                      // h1(p) -> v1next.h1
                bsplit(hA, h2, l2);
                vb[VOFF(nxt,1,0) + n16*72 + 32 + cA] = h2;  vb[VOFF(nxt,1,1) + n16*72 + 32 + cA] = l2;
                bsplit(hB, h2, l2);
                vb[VOFF(nxt,1,0) + n16*72 + 32 + cB] = h2;  vb[VOFF(nxt,1,1) + n16*72 + 32 + cB] = l2;
                if (p == 11 && n16 < SQ) { sh1f[n16*32 + cA] = hA; sh1f[n16*32 + cB] = hB; }
            }
        }
        if (tid < SQ*32 && p + 2 < 12) {                  // stage x(p+2) -> v0next.x
            int us = tid >> 5, uc = tid & 31;
            short h2, l2; bsplit(shg[us*384 + (p+2)*32 + uc], h2, l2);
            vb[VOFF(nxt,0,0) + us*72 + uc] = h2;  vb[VOFF(nxt,0,1) + us*72 + uc] = l2;
        }
        __syncthreads();
        cur = nxt;
    }

    // ---- FC: 180 outputs (5 seqs x 36) ----
    if (tid < SQ*36) {
        int s = tid / 36, r = tid - s*36;
        float acc = fcb[r];
        #pragma unroll
        for (int c4 = 0; c4 < 8; c4++) {
            float4 uv = *(const float4*)&fcW[r*32 + 4*c4];
            acc += uv.x*sh1f[s*32+4*c4+0] + uv.y*sh1f[s*32+4*c4+1]
                 + uv.z*sh1f[s*32+4*c4+2] + uv.w*sh1f[s*32+4*c4+3];
        }
        out[(seq0 + s)*36 + r] = acc;
    }
}

extern "C" void kernel_launch(void* const* d_in, const int* in_sizes, int n_in,
                              void* d_out, int out_size, void* d_ws, size_t ws_size,
                              hipStream_t stream)
{
    const float* A    = (const float*)d_in[0];
    const float* X    = (const float*)d_in[1];
    const float* Wg   = (const float*)d_in[2];
    const float* aat  = (const float*)d_in[3];
    const float* Wih0 = (const float*)d_in[4];
    const float* Whh0 = (const float*)d_in[5];
    const float* bih0 = (const float*)d_in[6];
    const float* bhh0 = (const float*)d_in[7];
    const float* Wih1 = (const float*)d_in[8];
    const float* Whh1 = (const float*)d_in[9];
    const float* bih1 = (const float*)d_in[10];
    const float* bhh1 = (const float*)d_in[11];
    const float* fcW  = (const float*)d_in[12];
    const float* fcb  = (const float*)d_in[13];
    float* out = (float*)d_out;

    k_stgat<<<480, 512, 0, stream>>>(A, X, Wg, aat,
                                     Wih0, Whh0, bih0, bhh0,
                                     Wih1, Whh1, bih1, bhh1,
                                     fcW, fcb, out);
}